// Round 1
// 473.456 us; speedup vs baseline: 1.0225x; 1.0225x over previous
//
#include <hip/hip_runtime.h>
#include <math.h>

typedef __attribute__((ext_vector_type(8))) __bf16 bf16x8;
typedef __attribute__((ext_vector_type(4))) __bf16 bf16x4;
typedef __attribute__((ext_vector_type(4))) float f32x4;

// max over the 16-lane group via DPP row rotations (VALU, not LDS pipe)
__device__ __forceinline__ float rowmax16(float x) {
    int xi = __builtin_bit_cast(int, x);
    float y;
    y = __builtin_bit_cast(float, __builtin_amdgcn_update_dpp(0, xi, 0x128, 0xf, 0xf, true)); // ror:8
    x = fmaxf(x, y); xi = __builtin_bit_cast(int, x);
    y = __builtin_bit_cast(float, __builtin_amdgcn_update_dpp(0, xi, 0x124, 0xf, 0xf, true)); // ror:4
    x = fmaxf(x, y); xi = __builtin_bit_cast(int, x);
    y = __builtin_bit_cast(float, __builtin_amdgcn_update_dpp(0, xi, 0x122, 0xf, 0xf, true)); // ror:2
    x = fmaxf(x, y); xi = __builtin_bit_cast(int, x);
    y = __builtin_bit_cast(float, __builtin_amdgcn_update_dpp(0, xi, 0x121, 0xf, 0xf, true)); // ror:1
    x = fmaxf(x, y);
    return x;
}

// ---------------------------------------------------------------------------
// prep: transpose + bf16-cast the three epilogue weight matrices.
// ---------------------------------------------------------------------------
__global__ void prep_kernel(const float* __restrict__ wlin,
                            const float* __restrict__ wu2,
                            const float* __restrict__ wsc,
                            __bf16* __restrict__ wlinT,
                            __bf16* __restrict__ wu2T,
                            __bf16* __restrict__ wscT)
{
    int i = blockIdx.x * 256 + threadIdx.x;
    if (i < 64 * 512) {
        int l = i >> 9, k = i & 511;
        wlinT[i] = (__bf16)wlin[k * 64 + l];
    } else if (i < 64 * 512 + 128 * 64) {
        int j = i - 64 * 512; int co = j >> 6, kk = j & 63;
        wu2T[j] = (__bf16)wu2[kk * 128 + co];
    } else if (i < 64 * 512 + 2 * 128 * 64) {
        int j = i - 64 * 512 - 128 * 64; int co = j >> 6, kk = j & 63;
        wscT[j] = (__bf16)wsc[kk * 128 + co];
    }
}

// ---------------------------------------------------------------------------
// Kernel A v2: one thread = one point. Inputs live in VGPRs; weight reads are
// thread-uniform -> compiler emits s_load + v_fmac(v,s,v). Zero LDS usage,
// zero barriers. Previous version was LDS-pipe-bound (2-3 ds_read per FMA).
// ---------------------------------------------------------------------------
__global__ __launch_bounds__(256) void feats_kernel(
    const float* __restrict__ df,
    const float* __restrict__ w1, const float* __restrict__ b1,
    const float* __restrict__ wg, const float* __restrict__ bg,
    float* __restrict__ fx, float* __restrict__ gx, int N)
{
    long n = (long)blockIdx.x * 256 + threadIdx.x;
    if (n >= N) return;

    float in[64];
    {
        const float4* p4 = (const float4*)(df + n * 64);
#pragma unroll
        for (int i = 0; i < 16; i++) {
            float4 a = p4[i];
            in[i * 4 + 0] = a.x; in[i * 4 + 1] = a.y;
            in[i * 4 + 2] = a.z; in[i * 4 + 3] = a.w;
        }
    }

    float acc[32];
#pragma unroll
    for (int c = 0; c < 32; c++) acc[c] = b1[c];
#pragma unroll
    for (int i = 0; i < 64; i++) {
        float x = in[i];
#pragma unroll
        for (int c = 0; c < 32; c++) acc[c] += x * w1[i * 32 + c];   // w1 idx uniform -> SGPR
    }
#pragma unroll
    for (int c = 0; c < 32; c++) acc[c] = acc[c] > 0.f ? acc[c] : 0.1f * acc[c];

    {
        float4* fo = (float4*)(fx + n * 32);
#pragma unroll
        for (int c4 = 0; c4 < 8; c4++)
            fo[c4] = make_float4(acc[c4 * 4 + 0], acc[c4 * 4 + 1],
                                 acc[c4 * 4 + 2], acc[c4 * 4 + 3]);
    }

    float g[32];
#pragma unroll
    for (int c = 0; c < 32; c++) g[c] = bg[c];
#pragma unroll
    for (int i = 0; i < 32; i++) {
        float x = acc[i];
#pragma unroll
        for (int c = 0; c < 32; c++) g[c] += x * wg[i * 32 + c];     // uniform -> SGPR
    }
    {
        float4* go = (float4*)(gx + n * 32);
#pragma unroll
        for (int c4 = 0; c4 < 8; c4++)
            go[c4] = make_float4(g[c4 * 4 + 0], g[c4 * 4 + 1],
                                 g[c4 * 4 + 2], g[c4 * 4 + 3]);
    }
}

// ---------------------------------------------------------------------------
// Kernel B: 16 sparse points / 256-thread block.
// phase1: per-(p,q) fp32 VALU pipeline -> nf(bf16), w3(bf16), sf(bf16) in LDS
// phase2: agg[p][512] (fp32 accum) -> bf16 LDS, k-contiguous per thread
// phase3: MFMA 16x16x32 bf16: out64 = relu(agg @ wlinT^T + blin)
// phase4: MFMA: out = leaky(out64 @ wu2 + sf @ wsc + b), staged through LDS
//         (reusing dead aggB region) so global writes are full coalesced rows.
// LDS total 38400 B -> 4 blocks/CU.
// ---------------------------------------------------------------------------
struct SmemU {
    union {
        struct { __bf16 nfb[16][16][40]; __bf16 w3b[16][16][24]; } a; // 32768 B
        __bf16 aggB[16][520];                                         // 16640 B
        float  outS[16][128];                                         //  8192 B
    };
};

__global__ __launch_bounds__(256, 4) void pcf_kernel(
    const float* __restrict__ vi, const int* __restrict__ nei,
    const float* __restrict__ df,
    const float* __restrict__ fx, const float* __restrict__ gx,
    const float* __restrict__ wpe, const float* __restrict__ bpe,
    const float* __restrict__ wg1, const float* __restrict__ bg1,
    const float* __restrict__ wg2, const float* __restrict__ bg2,
    const float* __restrict__ wn1, const float* __restrict__ bn1,
    const float* __restrict__ wn2, const float* __restrict__ bn2,
    const float* __restrict__ wn3, const float* __restrict__ bn3,
    const __bf16* __restrict__ wlinT, const float* __restrict__ blin,
    const __bf16* __restrict__ wu2T, const float* __restrict__ bu2,
    const __bf16* __restrict__ wscT, const float* __restrict__ bsc,
    float* __restrict__ out, int M)
{
    __shared__ SmemU U;
    __shared__ __bf16 sO[16][72];     // out64, padded rows (144B)
    __shared__ __bf16 sS[16][72];     // shortcut maxpool
    __shared__ int sInd[16][16];

    int t = threadIdx.x;
    int p = t >> 4, q = t & 15;
    long mbase = (long)blockIdx.x * 16;
    long m = mbase + p;
    bool okm = m < (long)M;
    int ind = okm ? nei[m * 16 + q] : 0;
    sInd[p][q] = ind;                 // consumed within the same wave only

    // ---------------- phase 1 ----------------
    float v[12];
    {
        const float4* v4 = (const float4*)(vi + (okm ? (m * 16 + q) * 12 : 0));
        float4 a = v4[0], b = v4[1], cc = v4[2];
        v[0] = a.x; v[1] = a.y; v[2] = a.z; v[3] = a.w;
        v[4] = b.x; v[5] = b.y; v[6] = b.z; v[7] = b.w;
        v[8] = cc.x; v[9] = cc.y; v[10] = cc.z; v[11] = cc.w;
    }
    float pe[32];
#pragma unroll
    for (int c = 0; c < 32; c++) {
        float a = bpe[c];
#pragma unroll
        for (int i = 0; i < 12; i++) a += v[i] * wpe[i * 32 + c];
        pe[c] = fmaxf(a, 0.f);
    }
    float gd[32];
    {
        const float4* g4 = (const float4*)(gx + (long)ind * 32);
#pragma unroll
        for (int c8 = 0; c8 < 8; c8++) {
            float4 gg = g4[c8];
            gd[c8 * 4 + 0] = gg.x; gd[c8 * 4 + 1] = gg.y;
            gd[c8 * 4 + 2] = gg.z; gd[c8 * 4 + 3] = gg.w;
        }
    }
    float s1[8];
#pragma unroll
    for (int j = 0; j < 8; j++) s1[j] = bg1[j];
#pragma unroll
    for (int i = 0; i < 64; i++) {
        float gi = (i < 32) ? gd[i] : pe[i - 32];
        float sub = gi - rowmax16(gi);
#pragma unroll
        for (int j = 0; j < 8; j++) s1[j] += sub * wg1[i * 8 + j];
    }
#pragma unroll
    for (int j = 0; j < 8; j++) s1[j] = fmaxf(s1[j], 0.f);
    float s2[8];
#pragma unroll
    for (int j = 0; j < 8; j++) {
        float a = bg2[j];
#pragma unroll
        for (int i = 0; i < 8; i++) a += s1[i] * wg2[i * 8 + j];
        s2[j] = 1.f / (1.f + __expf(-a));
    }
    float wa[8], wb[8];
#pragma unroll
    for (int j = 0; j < 8; j++) {
        float a = bn1[j];
#pragma unroll
        for (int i = 0; i < 12; i++) a += v[i] * wn1[i * 8 + j];
        wa[j] = fmaxf(a, 0.f);
    }
#pragma unroll
    for (int j = 0; j < 8; j++) {
        float a = bn2[j];
#pragma unroll
        for (int i = 0; i < 8; i++) a += wa[i] * wn2[i * 8 + j];
        wb[j] = fmaxf(a, 0.f);
    }
    {
        float w3v[16];
#pragma unroll
        for (int j = 0; j < 16; j++) {
            float a = bn3[j];
#pragma unroll
            for (int i = 0; i < 8; i++) a += wb[i] * wn3[i * 16 + j];
            w3v[j] = fmaxf(a, 0.f);
        }
        bf16x8 wlo, whi;
#pragma unroll
        for (int jj = 0; jj < 8; jj++) { wlo[jj] = (__bf16)w3v[jj]; whi[jj] = (__bf16)w3v[8 + jj]; }
        *(bf16x8*)(&U.a.w3b[p][q][0]) = wlo;
        *(bf16x8*)(&U.a.w3b[p][q][8]) = whi;
    }
    {
        const float4* f4 = (const float4*)(fx + (long)ind * 32);
        float nfv[32];
#pragma unroll
        for (int c8 = 0; c8 < 8; c8++) {
            float4 f = f4[c8];
            float s = s2[c8];
            nfv[c8 * 4 + 0] = f.x * s; nfv[c8 * 4 + 1] = f.y * s;
            nfv[c8 * 4 + 2] = f.z * s; nfv[c8 * 4 + 3] = f.w * s;
        }
#pragma unroll
        for (int g = 0; g < 4; g++) {
            bf16x8 pk;
#pragma unroll
            for (int e = 0; e < 8; e++) pk[e] = (__bf16)nfv[g * 8 + e];
            *(bf16x8*)(&U.a.nfb[p][q][g * 8]) = pk;
        }
    }
    {
        float4 mx = make_float4(-1e30f, -1e30f, -1e30f, -1e30f);
#pragma unroll
        for (int kk = 0; kk < 16; kk++) {
            int ik = sInd[p][kk];
            float4 d = *(const float4*)(df + (long)ik * 64 + q * 4);
            mx.x = fmaxf(mx.x, d.x); mx.y = fmaxf(mx.y, d.y);
            mx.z = fmaxf(mx.z, d.z); mx.w = fmaxf(mx.w, d.w);
        }
        bf16x4 pk;
        pk[0] = (__bf16)mx.x; pk[1] = (__bf16)mx.y; pk[2] = (__bf16)mx.z; pk[3] = (__bf16)mx.w;
        *(bf16x4*)(&sS[p][q * 4]) = pk;
    }
    __syncthreads();

    // ---------------- phase 2: agg[p][k], k = c*16 + j ----------------
    {
        int chalf = q >> 1, j0 = (q & 1) * 8;
        float acc[4][8];
#pragma unroll
        for (int c4 = 0; c4 < 4; c4++)
#pragma unroll
            for (int j = 0; j < 8; j++) acc[c4][j] = 0.f;
#pragma unroll
        for (int kk = 0; kk < 16; kk++) {
            bf16x8 w8 = *(const bf16x8*)(&U.a.w3b[p][kk][j0]);
            float wf[8];
#pragma unroll
            for (int e = 0; e < 8; e++) wf[e] = (float)w8[e];
#pragma unroll
            for (int c4 = 0; c4 < 4; c4++) {
                float nfc = (float)U.a.nfb[p][kk][c4 * 8 + chalf];
#pragma unroll
                for (int j = 0; j < 8; j++) acc[c4][j] += nfc * wf[j];
            }
        }
        __syncthreads();          // all union-a reads complete before overwrite
#pragma unroll
        for (int c4 = 0; c4 < 4; c4++) {
            bf16x8 pk;
#pragma unroll
            for (int j = 0; j < 8; j++) pk[j] = (__bf16)acc[c4][j];
            *(bf16x8*)(&U.aggB[p][c4 * 128 + q * 8]) = pk;
        }
    }
    __syncthreads();

    // ---------------- phase 3: out64 = relu(agg @ wlin + blin), MFMA --------
    {
        int wv = t >> 6, ln = t & 63;
        int n = ln & 15, quad = ln >> 4;
        const __bf16* Bp = wlinT + ((wv * 16 + n) * 512 + quad * 8);
        f32x4 acc = {0.f, 0.f, 0.f, 0.f};
#pragma unroll
        for (int kk = 0; kk < 16; kk++) {
            bf16x8 a = *(const bf16x8*)(&U.aggB[n][kk * 32 + quad * 8]);
            bf16x8 b = *(const bf16x8*)(Bp + kk * 32);
            acc = __builtin_amdgcn_mfma_f32_16x16x32_bf16(a, b, acc, 0, 0, 0);
        }
        int col = wv * 16 + n;
        float bl = blin[col];
#pragma unroll
        for (int r = 0; r < 4; r++) {
            int row = quad * 4 + r;
            sO[row][col] = (__bf16)fmaxf(acc[r] + bl, 0.f);
        }
    }
    __syncthreads();

    // ---------------- phase 4: out = leaky(out64@wu2 + sf@wsc + b), MFMA ----
    // results staged in LDS (aggB region is dead), then written as full rows.
    {
        int wv = t >> 6, ln = t & 63;
        int n = ln & 15, quad = ln >> 4;
        bf16x8 aO0 = *(const bf16x8*)(&sO[n][quad * 8]);
        bf16x8 aO1 = *(const bf16x8*)(&sO[n][32 + quad * 8]);
        bf16x8 aS0 = *(const bf16x8*)(&sS[n][quad * 8]);
        bf16x8 aS1 = *(const bf16x8*)(&sS[n][32 + quad * 8]);
#pragma unroll
        for (int tt = 0; tt < 2; tt++) {
            int T = wv * 2 + tt;
            int col = T * 16 + n;
            const __bf16* B1 = wu2T + (col * 64 + quad * 8);
            const __bf16* B2 = wscT + (col * 64 + quad * 8);
            f32x4 acc = {0.f, 0.f, 0.f, 0.f};
            acc = __builtin_amdgcn_mfma_f32_16x16x32_bf16(aO0, *(const bf16x8*)(B1), acc, 0, 0, 0);
            acc = __builtin_amdgcn_mfma_f32_16x16x32_bf16(aO1, *(const bf16x8*)(B1 + 32), acc, 0, 0, 0);
            acc = __builtin_amdgcn_mfma_f32_16x16x32_bf16(aS0, *(const bf16x8*)(B2), acc, 0, 0, 0);
            acc = __builtin_amdgcn_mfma_f32_16x16x32_bf16(aS1, *(const bf16x8*)(B2 + 32), acc, 0, 0, 0);
            float bb = bu2[col] + bsc[col];
#pragma unroll
            for (int r = 0; r < 4; r++) {
                float x = acc[r] + bb;
                U.outS[quad * 4 + r][col] = x > 0.f ? x : 0.1f * x;
            }
        }
    }
    __syncthreads();
    {
        int row = t >> 4;
        long mm = mbase + row;
        if (mm < (long)M) {
            const float4* src = (const float4*)(&U.outS[row][0]) + (t & 15) * 2;
            float4* dst = (float4*)(out + mm * 128) + (t & 15) * 2;
            dst[0] = src[0];
            dst[1] = src[1];
        }
    }
}

extern "C" void kernel_launch(void* const* d_in, const int* in_sizes, int n_in,
                              void* d_out, int out_size, void* d_ws, size_t ws_size,
                              hipStream_t stream)
{
    const float* dense_feats = (const float*)d_in[1];
    const float* vi    = (const float*)d_in[5];
    const int*   nei   = (const int*)d_in[6];
    const float* w_u1  = (const float*)d_in[7];
    const float* b_u1  = (const float*)d_in[8];
    const float* w_gu  = (const float*)d_in[9];
    const float* b_gu  = (const float*)d_in[10];
    const float* w_pe  = (const float*)d_in[11];
    const float* b_pe  = (const float*)d_in[12];
    const float* w_g1  = (const float*)d_in[13];
    const float* b_g1  = (const float*)d_in[14];
    const float* w_g2  = (const float*)d_in[15];
    const float* b_g2  = (const float*)d_in[16];
    const float* w_wn1 = (const float*)d_in[17];
    const float* b_wn1 = (const float*)d_in[18];
    const float* w_wn2 = (const float*)d_in[19];
    const float* b_wn2 = (const float*)d_in[20];
    const float* w_wn3 = (const float*)d_in[21];
    const float* b_wn3 = (const float*)d_in[22];
    const float* w_lin = (const float*)d_in[23];
    const float* b_lin = (const float*)d_in[24];
    const float* w_u2  = (const float*)d_in[25];
    const float* b_u2  = (const float*)d_in[26];
    const float* w_sc  = (const float*)d_in[27];
    const float* b_sc  = (const float*)d_in[28];

    int N = in_sizes[1] / 64;     // 200000
    int M = in_sizes[6] / 16;     // 100000

    float* fx  = (float*)d_ws;                    // [N,32] f32
    float* gxp = fx + (size_t)N * 32;             // [N,32] f32
    __bf16* wlinT = (__bf16*)(gxp + (size_t)N * 32);  // [64,512]
    __bf16* wu2T  = wlinT + 64 * 512;                  // [128,64]
    __bf16* wscT  = wu2T + 128 * 64;                   // [128,64]

    prep_kernel<<<(64 * 512 + 2 * 128 * 64 + 255) / 256, 256, 0, stream>>>(
        w_lin, w_u2, w_sc, wlinT, wu2T, wscT);

    feats_kernel<<<(N + 255) / 256, 256, 0, stream>>>(
        dense_feats, w_u1, b_u1, w_gu, b_gu, fx, gxp, N);

    pcf_kernel<<<(M + 15) / 16, 256, 0, stream>>>(
        vi, nei, dense_feats, fx, gxp,
        w_pe, b_pe, w_g1, b_g1, w_g2, b_g2,
        w_wn1, b_wn1, w_wn2, b_wn2, w_wn3, b_wn3,
        wlinT, b_lin, wu2T, b_u2, wscT, b_sc,
        (float*)d_out, M);
}